// Round 5
// baseline (409.326 us; speedup 1.0000x reference)
//
#include <hip/hip_runtime.h>
#include <hip/hip_cooperative_groups.h>
#include <math.h>

namespace cg = cooperative_groups;

#define NT 2560
#define DF 32
#define NB 4
#define SELF_EPS 0.5f
#define WREG 12032           // per-wave LDS region bytes
#define MITW 20              // m-iters per wave (each wave covers NT/2 = 1280 rows)

typedef __attribute__((ext_vector_type(8))) short bf16x8;
typedef __attribute__((ext_vector_type(4))) float f32x4;

__device__ __forceinline__ unsigned short f2bf(float f) {
    unsigned u = __builtin_bit_cast(unsigned, f);
    u += 0x7fffu + ((u >> 16) & 1u);   // RNE
    return (unsigned short)(u >> 16);
}
__device__ __forceinline__ float fast_rcp(float x) {
#if __has_builtin(__builtin_amdgcn_rcpf)
    return __builtin_amdgcn_rcpf(x);
#else
    return 1.0f / x;
#endif
}
__device__ __forceinline__ float fast_exp2(float x) {
#if __has_builtin(__builtin_amdgcn_exp2f)
    return __builtin_amdgcn_exp2f(x);
#else
    return exp2f(x);
#endif
}
// tanh(relu(x)) = 1 - 2/(exp2(2*log2e*x)+1) for x>=0
__device__ __forceinline__ float tanh_relu(float x) {
    float m = fmaxf(x, 0.0f);
    float e = fast_exp2(m * 2.885390082f);
    return 1.0f - 2.0f * fast_rcp(e + 1.0f);
}
__device__ __forceinline__ float elu(float x) {
    return x > 0.f ? x : fast_exp2(x * 1.442695041f) - 1.f;
}

// Per-wave LDS region (12032 B x 2 waves):
//   [0,     2304)  S  : 16n x 64m bf16 (stride 72 shorts); fp32 16x33 park after loop
//   [2304,  7424)  Xm : 64m x 32k bf16 (stride 40 shorts)
//   [7424, 12032)  Ht : 32d x 64m bf16 (stride 72 shorts)
// Epilogue scratch: sAgg=w0.Xm[0..2112), sOut=w0.Xm[2112..4224), sH=w0.Ht,
//                   sW=w1.Xm, sN=w1.Ht — none alias the S park areas.

// ---- phase 0 body: convert 16 rows of X -> Xb bf16 + XT bf16 (transposed) ----
__device__ __forceinline__ void prep_unit(const float* __restrict__ X,
                                          unsigned short* __restrict__ Xb,
                                          unsigned short* __restrict__ XT,
                                          char* smem, int t, int blk)
{
    const int b = blk & 3, n0p = (blk >> 2) * 16;
    float* sTp = (float*)smem;                  // [16][33]
    const int row = t >> 3, c4 = (t & 7) * 4;
    const size_t off = ((size_t)b * NT + n0p + row) * DF + c4;
    const float4 v = *(const float4*)(X + off);
    unsigned p0 = (unsigned)f2bf(v.x) | ((unsigned)f2bf(v.y) << 16);
    unsigned p1 = (unsigned)f2bf(v.z) | ((unsigned)f2bf(v.w) << 16);
    *(uint2*)(Xb + off) = make_uint2(p0, p1);
    sTp[row * 33 + c4 + 0] = v.x; sTp[row * 33 + c4 + 1] = v.y;
    sTp[row * 33 + c4 + 2] = v.z; sTp[row * 33 + c4 + 3] = v.w;
    __syncthreads();
    const int d = t >> 2, mp = (t & 3) * 4;
    unsigned q0 = (unsigned)f2bf(sTp[(mp + 0) * 33 + d])
                | ((unsigned)f2bf(sTp[(mp + 1) * 33 + d]) << 16);
    unsigned q1 = (unsigned)f2bf(sTp[(mp + 2) * 33 + d])
                | ((unsigned)f2bf(sTp[(mp + 3) * 33 + d]) << 16);
    *(uint2*)(XT + ((size_t)b * DF + d) * NT + n0p + mp) = make_uint2(q0, q1);
}

// ---- one layer for one (b, 16-row n-tile) unit; 2 waves, each half the m ----
__device__ __forceinline__ void layer_pass(
    const unsigned short* __restrict__ Xb,   // [B][NT][32] bf16
    const unsigned short* __restrict__ HT,   // [B][32][NT] bf16 transposed
    const float* __restrict__ Hin,           // [B][NT][32] fp32
    const float* __restrict__ Wsl, const float* __restrict__ Wnl,
    const float* __restrict__ bl,
    float* __restrict__ Hout,                // [B][NT][32] fp32
    unsigned short* __restrict__ HTout,      // [B][32][NT] bf16 or nullptr
    char* smem, int t, int blk)
{
    const int b  = blk & 3;
    const int n0 = (blk >> 2) * 16;
    const int w = t >> 6, lane = t & 63;
    const int q = lane >> 4, c = lane & 15;
    const size_t xbase = (size_t)b * NT * DF;
    const size_t tbase = (size_t)b * DF * NT;

    unsigned short* Sw = (unsigned short*)(smem + w * WREG);
    unsigned short* Xw = (unsigned short*)(smem + w * WREG + 2304);
    unsigned short* Hw = (unsigned short*)(smem + w * WREG + 7424);

    // score B-frag: Xn[n=n0+c][k=q*8..], loop-invariant, same for both waves
    const bf16x8 bfn = *(const bf16x8*)(Xb + xbase + (size_t)(n0 + c) * DF + q * 8);

    f32x4 acc0 = {0.f, 0.f, 0.f, 0.f};
    f32x4 acc1 = {0.f, 0.f, 0.f, 0.f};
    const int wbase = w * (NT / 2);
    const int hd = lane & 31, hh = lane >> 5;

    // prefetch iter 0
    uint4 xv[4], hv[4];
    {
        const unsigned short* xs = Xb + xbase + (size_t)(wbase + lane) * DF;
        const unsigned short* hs = HT + tbase + (size_t)hd * NT + wbase + hh * 32;
        #pragma unroll
        for (int k = 0; k < 4; ++k) {
            xv[k] = *(const uint4*)(xs + k * 8);
            hv[k] = *(const uint4*)(hs + k * 8);
        }
    }

    for (int it = 0; it < MITW; ++it) {
        const int m0 = wbase + it * 64;
        // ---- stage current tiles from prefetch regs ----
        #pragma unroll
        for (int k = 0; k < 4; ++k) {
            *(uint4*)(Xw + lane * 40 + k * 8) = xv[k];
            *(uint4*)(Hw + hd * 72 + hh * 32 + k * 8) = hv[k];
        }
        if (it + 1 < MITW) {   // prefetch next iter
            const int m1 = m0 + 64;
            const unsigned short* xs = Xb + xbase + (size_t)(m1 + lane) * DF;
            const unsigned short* hs = HT + tbase + (size_t)hd * NT + m1 + hh * 32;
            #pragma unroll
            for (int k = 0; k < 4; ++k) {
                xv[k] = *(const uint4*)(xs + k * 8);
                hv[k] = *(const uint4*)(hs + k * 8);
            }
        }
        asm volatile("s_waitcnt lgkmcnt(0)" ::: "memory");  // staging visible wave-wide

        // ---- scores: lane holds S[n=c][m = m0 + t4*16 + q*4 + r] ----
        #pragma unroll
        for (int t4 = 0; t4 < 4; ++t4) {
            const bf16x8 af = *(const bf16x8*)(Xw + (t4 * 16 + c) * 40 + q * 8);
            const f32x4 zero = {0.f, 0.f, 0.f, 0.f};
            f32x4 st = __builtin_amdgcn_mfma_f32_16x16x32_bf16(af, bfn, zero, 0, 0, 0);
            float v0 = tanh_relu(st[0]);
            float v1 = tanh_relu(st[1]);
            float v2 = tanh_relu(st[2]);
            float v3 = tanh_relu(st[3]);
            if ((m0 + t4 * 16 == n0) && (q == (c >> 2))) {   // diagonal tile
                const int r = c & 3;
                v0 += (r == 0) ? SELF_EPS : 0.f;
                v1 += (r == 1) ? SELF_EPS : 0.f;
                v2 += (r == 2) ? SELF_EPS : 0.f;
                v3 += (r == 3) ? SELF_EPS : 0.f;
            }
            unsigned p0 = (unsigned)f2bf(v0) | ((unsigned)f2bf(v1) << 16);
            unsigned p1 = (unsigned)f2bf(v2) | ((unsigned)f2bf(v3) << 16);
            *(uint2*)(Sw + c * 72 + t4 * 16 + q * 4) = make_uint2(p0, p1);
        }
        asm volatile("s_waitcnt lgkmcnt(0)" ::: "memory");  // S visible wave-wide

        // ---- agg: acc[n][d] += S[n][m] * H[m][d] ----
        #pragma unroll
        for (int kc = 0; kc < 2; ++kc) {
            const bf16x8 sf  = *(const bf16x8*)(Sw + c * 72 + kc * 32 + q * 8);
            const bf16x8 h0  = *(const bf16x8*)(Hw + c * 72 + kc * 32 + q * 8);
            const bf16x8 h1v = *(const bf16x8*)(Hw + (16 + c) * 72 + kc * 32 + q * 8);
            acc0 = __builtin_amdgcn_mfma_f32_16x16x32_bf16(sf, h0, acc0, 0, 0, 0);
            acc1 = __builtin_amdgcn_mfma_f32_16x16x32_bf16(sf, h1v, acc1, 0, 0, 0);
        }
    }

    // ---- park per-wave partials in own S area (16n x 33 fp32) ----
    float* sF = (float*)(smem + w * WREG);
    #pragma unroll
    for (int r = 0; r < 4; ++r) {
        sF[(q * 4 + r) * 33 + c]      = acc0[r];
        sF[(q * 4 + r) * 33 + c + 16] = acc1[r];
    }
    __syncthreads();

    float* sAgg = (float*)(smem + 2304);
    float* sOut = (float*)(smem + 2304 + 2112);
    float* sH   = (float*)(smem + 7424);
    float* sW   = (float*)(smem + WREG + 2304);
    float* sN   = (float*)(smem + WREG + 7424);

    const int rn = t >> 3, c4 = (t & 7) * 4;
    {   // reduce 2 waves; stage Hin row; stage weights (2 rows each)
        const float* f0 = (const float*)(smem);
        const float* f1 = (const float*)(smem + WREG);
        #pragma unroll
        for (int j = 0; j < 4; ++j)
            sAgg[rn * 33 + c4 + j] = f0[rn * 33 + c4 + j] + f1[rn * 33 + c4 + j];
        const float4 hvv = *(const float4*)(Hin + ((size_t)b * NT + n0 + rn) * DF + c4);
        sH[rn * 33 + c4 + 0] = hvv.x; sH[rn * 33 + c4 + 1] = hvv.y;
        sH[rn * 33 + c4 + 2] = hvv.z; sH[rn * 33 + c4 + 3] = hvv.w;
        #pragma unroll
        for (int h = 0; h < 2; ++h) {
            const int k = rn + h * 16;
            const float4 w0 = *(const float4*)(Wsl + k * DF + c4);
            const float4 w1 = *(const float4*)(Wnl + k * DF + c4);
            sW[k * 33 + c4 + 0] = w0.x; sW[k * 33 + c4 + 1] = w0.y;
            sW[k * 33 + c4 + 2] = w0.z; sW[k * 33 + c4 + 3] = w0.w;
            sN[k * 33 + c4 + 0] = w1.x; sN[k * 33 + c4 + 1] = w1.y;
            sN[k * 33 + c4 + 2] = w1.z; sN[k * 33 + c4 + 3] = w1.w;
        }
    }
    __syncthreads();

    // ---- epilogue: z = elu(h·Ws + agg·Wn + b), 4 outputs per thread ----
    float z0 = bl[c4 + 0], z1 = bl[c4 + 1], z2 = bl[c4 + 2], z3 = bl[c4 + 3];
    #pragma unroll
    for (int k = 0; k < DF; ++k) {
        const float hk = sH[rn * 33 + k], ak = sAgg[rn * 33 + k];
        z0 += hk * sW[k * 33 + c4 + 0] + ak * sN[k * 33 + c4 + 0];
        z1 += hk * sW[k * 33 + c4 + 1] + ak * sN[k * 33 + c4 + 1];
        z2 += hk * sW[k * 33 + c4 + 2] + ak * sN[k * 33 + c4 + 2];
        z3 += hk * sW[k * 33 + c4 + 3] + ak * sN[k * 33 + c4 + 3];
    }
    z0 = elu(z0); z1 = elu(z1); z2 = elu(z2); z3 = elu(z3);
    *(float4*)(Hout + ((size_t)b * NT + n0 + rn) * DF + c4) =
        make_float4(z0, z1, z2, z3);

    if (HTout != nullptr) {   // uniform branch: emit transposed bf16 copy
        sOut[rn * 33 + c4 + 0] = z0; sOut[rn * 33 + c4 + 1] = z1;
        sOut[rn * 33 + c4 + 2] = z2; sOut[rn * 33 + c4 + 3] = z3;
        __syncthreads();
        const int d = t >> 2, mp = (t & 3) * 4;
        unsigned q0 = (unsigned)f2bf(sOut[(mp + 0) * 33 + d])
                    | ((unsigned)f2bf(sOut[(mp + 1) * 33 + d]) << 16);
        unsigned q1 = (unsigned)f2bf(sOut[(mp + 2) * 33 + d])
                    | ((unsigned)f2bf(sOut[(mp + 3) * 33 + d]) << 16);
        *(uint2*)(HTout + ((size_t)b * DF + d) * NT + n0 + mp) = make_uint2(q0, q1);
    }
}

// ---------------- cooperative single-dispatch kernel ----------------
__global__ __launch_bounds__(128, 2)
void fused(const float* __restrict__ X, const float* __restrict__ Ws,
           const float* __restrict__ Wn, const float* __restrict__ bv,
           float* __restrict__ out, float* __restrict__ h1,
           unsigned short* __restrict__ Xb, unsigned short* __restrict__ XT,
           unsigned short* __restrict__ H1T)
{
    __shared__ __align__(16) char smem[2 * WREG];   // 24064 B
    cg::grid_group grid = cg::this_grid();
    const int t = threadIdx.x, blk = blockIdx.x;

    prep_unit(X, Xb, XT, smem, t, blk);
    __threadfence();
    grid.sync();

    layer_pass(Xb, XT, X, Ws, Wn, bv, h1, H1T, smem, t, blk);
    __threadfence();
    grid.sync();

    layer_pass(Xb, H1T, h1, Ws + DF * DF, Wn + DF * DF, bv + DF,
               out, nullptr, smem, t, blk);
}

// ---------------- non-cooperative fallback kernels ----------------
__global__ __launch_bounds__(128, 2)
void k_prep(const float* __restrict__ X, unsigned short* __restrict__ Xb,
            unsigned short* __restrict__ XT)
{
    __shared__ __align__(16) char smem[2 * WREG];
    prep_unit(X, Xb, XT, smem, threadIdx.x, blockIdx.x);
}

__global__ __launch_bounds__(128, 2)
void k_layer(const unsigned short* __restrict__ Xb,
             const unsigned short* __restrict__ HT,
             const float* __restrict__ Hin,
             const float* __restrict__ Wsl, const float* __restrict__ Wnl,
             const float* __restrict__ bl,
             float* __restrict__ Hout, unsigned short* __restrict__ HTout)
{
    __shared__ __align__(16) char smem[2 * WREG];
    layer_pass(Xb, HT, Hin, Wsl, Wnl, bl, Hout, HTout, smem,
               threadIdx.x, blockIdx.x);
}

extern "C" void kernel_launch(void* const* d_in, const int* in_sizes, int n_in,
                              void* d_out, int out_size, void* d_ws, size_t ws_size,
                              hipStream_t stream) {
    const float* X  = (const float*)d_in[0];
    const float* Ws = (const float*)d_in[1];   // [2][32][32]
    const float* Wn = (const float*)d_in[2];   // [2][32][32]
    const float* bv = (const float*)d_in[3];   // [2][32]
    float* out = (float*)d_out;

    char* ws = (char*)d_ws;
    float* h1 = (float*)ws;                                   // 1,310,720 B
    unsigned short* Xb  = (unsigned short*)(ws + 1310720);    // 655,360 B
    unsigned short* XT  = Xb + (size_t)NB * NT * DF;          // 655,360 B
    unsigned short* H1T = XT + (size_t)NB * NT * DF;          // 655,360 B

    const float* Ws1 = Ws + DF * DF;
    const float* Wn1 = Wn + DF * DF;
    const float* bv1 = bv + DF;

    void* args[] = {(void*)&X, (void*)&Ws, (void*)&Wn, (void*)&bv,
                    (void*)&out, (void*)&h1, (void*)&Xb, (void*)&XT, (void*)&H1T};
    // 640 blocks of 128 thr; capacity 4 blocks/CU (1024) >> 640 — safe margin.
    hipError_t err = hipLaunchCooperativeKernel((const void*)fused,
                                                dim3(NB * (NT / 16)), dim3(128),
                                                args, 0, stream);
    if (err != hipSuccess) {
        // deterministic fallback: same math, 3 plain dispatches
        k_prep<<<dim3(NB * (NT / 16)), 128, 0, stream>>>(X, Xb, XT);
        k_layer<<<dim3(NB * (NT / 16)), 128, 0, stream>>>(Xb, XT, X, Ws, Wn, bv, h1, H1T);
        k_layer<<<dim3(NB * (NT / 16)), 128, 0, stream>>>(Xb, H1T, h1, Ws1, Wn1, bv1,
                                                          out, nullptr);
    }
}

// Round 6
// 192.864 us; speedup vs baseline: 2.1224x; 2.1224x over previous
//
#include <hip/hip_runtime.h>
#include <math.h>

#define NT 2560
#define DF 32
#define NB 4
#define SELF_EPS 0.5f
#define WREG 12800           // per-wave LDS region bytes

typedef __attribute__((ext_vector_type(8))) short bf16x8;
typedef __attribute__((ext_vector_type(4))) float f32x4;

__device__ __forceinline__ unsigned short f2bf(float f) {
    unsigned u = __builtin_bit_cast(unsigned, f);
    u += 0x7fffu + ((u >> 16) & 1u);   // RNE
    return (unsigned short)(u >> 16);
}
__device__ __forceinline__ float fast_rcp(float x) {
#if __has_builtin(__builtin_amdgcn_rcpf)
    return __builtin_amdgcn_rcpf(x);
#else
    return 1.0f / x;
#endif
}
__device__ __forceinline__ float fast_exp2(float x) {
#if __has_builtin(__builtin_amdgcn_exp2f)
    return __builtin_amdgcn_exp2f(x);
#else
    return exp2f(x);
#endif
}
// tanh(relu(x)) = 1 - 2/(exp2(2*log2e*x)+1) for x>=0
__device__ __forceinline__ float tanh_relu(float x) {
    float m = fmaxf(x, 0.0f);
    float e = fast_exp2(m * 2.885390082f);
    return 1.0f - 2.0f * fast_rcp(e + 1.0f);
}
__device__ __forceinline__ float elu(float x) {
    return x > 0.f ? x : fast_exp2(x * 1.442695041f) - 1.f;
}

// ---------------------------------------------------------------------------
// prep (round-2 verbatim, known good): X fp32 -> Xb bf16 [B][NT][32] and
// XT bf16 [B][32][NT]. 320 blocks x 256 thr.
// ---------------------------------------------------------------------------
__global__ __launch_bounds__(256, 4)
void prep(const float* __restrict__ X,
          unsigned short* __restrict__ Xb, unsigned short* __restrict__ XT)
{
    const int t = threadIdx.x;
    __shared__ float sT[32][33];
    const int tile = blockIdx.x;
    const int b = tile / 80, n0 = (tile % 80) * 32;
    const int row = t >> 3, c4 = (t & 7) * 4;
    const size_t rbase = ((size_t)(b * NT + n0 + row)) * DF + c4;
    const float4 v = *(const float4*)(X + rbase);
    unsigned p0 = (unsigned)f2bf(v.x) | ((unsigned)f2bf(v.y) << 16);
    unsigned p1 = (unsigned)f2bf(v.z) | ((unsigned)f2bf(v.w) << 16);
    *(uint2*)(Xb + rbase) = make_uint2(p0, p1);
    sT[row][c4 + 0] = v.x; sT[row][c4 + 1] = v.y;
    sT[row][c4 + 2] = v.z; sT[row][c4 + 3] = v.w;
    __syncthreads();
    const int d = t >> 3, nq = (t & 7) * 4;
    unsigned q0 = (unsigned)f2bf(sT[nq + 0][d]) | ((unsigned)f2bf(sT[nq + 1][d]) << 16);
    unsigned q1 = (unsigned)f2bf(sT[nq + 2][d]) | ((unsigned)f2bf(sT[nq + 3][d]) << 16);
    *(uint2*)(XT + ((size_t)(b * DF + d)) * NT + n0 + nq) = make_uint2(q0, q1);
}

// ---------------------------------------------------------------------------
// layer kernel: one block = one (batch, 16-row n-tile); 4 waves, each covering
// a disjoint quarter of the m-range (10 iters x 64 m). Scores + aggregation
// via MFMA per wave; in-block 4-wave reduction + dense epilogue + ELU fused.
// Per-wave LDS region (12800 B):
//   [0,    2560)  S  : 16n x 80 shorts (rows 160 B, 16B-aligned)
//   [2560, 7680)  Xw : 64m x 40 shorts (rows 80 B)
//   [7680,12800)  Hw : 32d x 80 shorts (rows 160 B)
// Epilogue scratch reuses Xw/Hw areas (parks live in the 4 S areas).
// ---------------------------------------------------------------------------
__global__ __launch_bounds__(256, 3)
void k_layer(const unsigned short* __restrict__ Xb,   // [B][NT][32] bf16
             const unsigned short* __restrict__ HT,   // [B][32][NT] bf16
             const float* __restrict__ Hin,           // [B][NT][32] fp32
             const float* __restrict__ Wsl, const float* __restrict__ Wnl,
             const float* __restrict__ bl,
             float* __restrict__ Hout,                // [B][NT][32] fp32
             unsigned short* __restrict__ HTout)      // [B][32][NT] bf16 or null
{
    __shared__ __align__(16) char smem[4 * WREG];     // 51200 B -> 3 blocks/CU
    const int t = threadIdx.x, blk = blockIdx.x;
    // XCD-aware swizzle: blk%8 = XCD on MI355X; keep one batch per XCD pair.
    const int g = blk & 7;
    const int b = g & 3;
    const int n0 = ((blk >> 3) + (g >> 2) * 80) * 16;
    const int w = t >> 6, lane = t & 63;
    const int q = lane >> 4, c = lane & 15;
    const size_t xbase = (size_t)b * NT * DF;
    const size_t tbase = (size_t)b * DF * NT;

    unsigned short* Sw = (unsigned short*)(smem + w * WREG);
    unsigned short* Xw = (unsigned short*)(smem + w * WREG + 2560);
    unsigned short* Hw = (unsigned short*)(smem + w * WREG + 7680);

    // score B-frag: Xn[n=n0+c][k=q*8..+7], loop-invariant
    const bf16x8 bfn = *(const bf16x8*)(Xb + xbase + (size_t)(n0 + c) * DF + q * 8);

    f32x4 acc0 = {0.f, 0.f, 0.f, 0.f};
    f32x4 acc1 = {0.f, 0.f, 0.f, 0.f};
    const int wbase = w * (NT / 4);

    // staging roles: Xm tile 4 lanes/row (16 rows x 64 B contiguous per instr);
    // Ht tile 8 lanes/d-row (8 rows x 128 B contiguous per instr).
    const int xr = lane >> 2, xs = lane & 3;
    const int hr = lane >> 3, hs = lane & 7;

    uint4 xv[4], hv[4];
    {   // prefetch iter 0
        const unsigned short* xp = Xb + xbase + (size_t)wbase * DF;
        const unsigned short* hp = HT + tbase + wbase;
        #pragma unroll
        for (int k = 0; k < 4; ++k) {
            xv[k] = *(const uint4*)(xp + (size_t)(k * 16 + xr) * DF + xs * 8);
            hv[k] = *(const uint4*)(hp + (size_t)(k * 8 + hr) * NT + hs * 8);
        }
    }

    for (int it = 0; it < 10; ++it) {
        const int m0 = wbase + it * 64;
        #pragma unroll
        for (int k = 0; k < 4; ++k) {
            *(uint4*)(Xw + (k * 16 + xr) * 40 + xs * 8) = xv[k];
            *(uint4*)(Hw + (k * 8 + hr) * 80 + hs * 8) = hv[k];
        }
        if (it + 1 < 10) {   // prefetch next iter
            const int m1 = m0 + 64;
            const unsigned short* xp = Xb + xbase + (size_t)m1 * DF;
            const unsigned short* hp = HT + tbase + m1;
            #pragma unroll
            for (int k = 0; k < 4; ++k) {
                xv[k] = *(const uint4*)(xp + (size_t)(k * 16 + xr) * DF + xs * 8);
                hv[k] = *(const uint4*)(hp + (size_t)(k * 8 + hr) * NT + hs * 8);
            }
        }
        asm volatile("s_waitcnt lgkmcnt(0)" ::: "memory");  // staging visible wave-wide

        // ---- scores: lane holds S[n=c][m = m0 + t4*16 + q*4 + r] ----
        #pragma unroll
        for (int t4 = 0; t4 < 4; ++t4) {
            const bf16x8 af = *(const bf16x8*)(Xw + (t4 * 16 + c) * 40 + q * 8);
            const f32x4 zero = {0.f, 0.f, 0.f, 0.f};
            f32x4 st = __builtin_amdgcn_mfma_f32_16x16x32_bf16(af, bfn, zero, 0, 0, 0);
            float v0 = tanh_relu(st[0]);
            float v1 = tanh_relu(st[1]);
            float v2 = tanh_relu(st[2]);
            float v3 = tanh_relu(st[3]);
            if ((m0 + t4 * 16 == n0) && (q == (c >> 2))) {   // diagonal tile
                const int r = c & 3;
                v0 += (r == 0) ? SELF_EPS : 0.f;
                v1 += (r == 1) ? SELF_EPS : 0.f;
                v2 += (r == 2) ? SELF_EPS : 0.f;
                v3 += (r == 3) ? SELF_EPS : 0.f;
            }
            unsigned p0 = (unsigned)f2bf(v0) | ((unsigned)f2bf(v1) << 16);
            unsigned p1 = (unsigned)f2bf(v2) | ((unsigned)f2bf(v3) << 16);
            *(uint2*)(Sw + c * 80 + t4 * 16 + q * 4) = make_uint2(p0, p1);
        }
        asm volatile("s_waitcnt lgkmcnt(0)" ::: "memory");  // S visible wave-wide

        // ---- agg: acc[n][d] += S[n][m] * H[m][d] ----
        #pragma unroll
        for (int kc = 0; kc < 2; ++kc) {
            const bf16x8 sf  = *(const bf16x8*)(Sw + c * 80 + kc * 32 + q * 8);
            const bf16x8 h0  = *(const bf16x8*)(Hw + c * 80 + kc * 32 + q * 8);
            const bf16x8 h1v = *(const bf16x8*)(Hw + (16 + c) * 80 + kc * 32 + q * 8);
            acc0 = __builtin_amdgcn_mfma_f32_16x16x32_bf16(sf, h0, acc0, 0, 0, 0);
            acc1 = __builtin_amdgcn_mfma_f32_16x16x32_bf16(sf, h1v, acc1, 0, 0, 0);
        }
    }

    // ---- park per-wave partials in own S area as [16][33] fp32 ----
    float* sF = (float*)(smem + w * WREG);
    #pragma unroll
    for (int r = 0; r < 4; ++r) {
        sF[(q * 4 + r) * 33 + c]      = acc0[r];
        sF[(q * 4 + r) * 33 + c + 16] = acc1[r];
    }
    __syncthreads();

    float* sAgg = (float*)(smem + 2560);              // w0.Xw
    float* sH   = (float*)(smem + 7680);              // w0.Hw
    float* sW   = (float*)(smem + WREG + 2560);       // w1.Xw
    float* sN   = (float*)(smem + WREG + 7680);       // w1.Hw
    float* sOut = (float*)(smem + 2 * WREG + 2560);   // w2.Xw

    const int rn = t >> 4, dp = (t & 15) * 2;
    {   // reduce 4 waves' partials (2 elems/thread)
        float a0 = 0.f, a1 = 0.f;
        #pragma unroll
        for (int w2 = 0; w2 < 4; ++w2) {
            const float* f = (const float*)(smem + w2 * WREG);
            a0 += f[rn * 33 + dp];
            a1 += f[rn * 33 + dp + 1];
        }
        sAgg[rn * 33 + dp]     = a0;
        sAgg[rn * 33 + dp + 1] = a1;
        const float2 hv2 = *(const float2*)(Hin + ((size_t)b * NT + n0 + rn) * DF + dp);
        sH[rn * 33 + dp]     = hv2.x;
        sH[rn * 33 + dp + 1] = hv2.y;
    }
    {   // stage weights 32x32 each (4 elems/thread)
        const int k = t >> 3, c4 = (t & 7) * 4;
        const float4 w0 = *(const float4*)(Wsl + k * DF + c4);
        const float4 w1 = *(const float4*)(Wnl + k * DF + c4);
        sW[k * 33 + c4 + 0] = w0.x; sW[k * 33 + c4 + 1] = w0.y;
        sW[k * 33 + c4 + 2] = w0.z; sW[k * 33 + c4 + 3] = w0.w;
        sN[k * 33 + c4 + 0] = w1.x; sN[k * 33 + c4 + 1] = w1.y;
        sN[k * 33 + c4 + 2] = w1.z; sN[k * 33 + c4 + 3] = w1.w;
    }
    __syncthreads();

    // ---- epilogue: z = elu(h·Ws + agg·Wn + b), 2 outputs per thread ----
    float z0 = bl[dp], z1 = bl[dp + 1];
    #pragma unroll
    for (int k = 0; k < DF; ++k) {
        const float hk = sH[rn * 33 + k], ak = sAgg[rn * 33 + k];
        z0 += hk * sW[k * 33 + dp]     + ak * sN[k * 33 + dp];
        z1 += hk * sW[k * 33 + dp + 1] + ak * sN[k * 33 + dp + 1];
    }
    z0 = elu(z0); z1 = elu(z1);
    *(float2*)(Hout + ((size_t)b * NT + n0 + rn) * DF + dp) = make_float2(z0, z1);

    if (HTout != nullptr) {   // uniform branch: emit transposed bf16 copy
        sOut[rn * 33 + dp]     = z0;
        sOut[rn * 33 + dp + 1] = z1;
        __syncthreads();
        const int d = t >> 3, mp = (t & 7) * 2;
        unsigned pv = (unsigned)f2bf(sOut[mp * 33 + d])
                    | ((unsigned)f2bf(sOut[(mp + 1) * 33 + d]) << 16);
        *(unsigned*)(HTout + ((size_t)b * DF + d) * NT + n0 + mp) = pv;
    }
}

extern "C" void kernel_launch(void* const* d_in, const int* in_sizes, int n_in,
                              void* d_out, int out_size, void* d_ws, size_t ws_size,
                              hipStream_t stream) {
    const float* X  = (const float*)d_in[0];
    const float* Ws = (const float*)d_in[1];   // [2][32][32]
    const float* Wn = (const float*)d_in[2];   // [2][32][32]
    const float* bv = (const float*)d_in[3];   // [2][32]
    float* out = (float*)d_out;

    char* ws = (char*)d_ws;
    float* h1 = (float*)ws;                                   // 1,310,720 B
    unsigned short* Xb  = (unsigned short*)(ws + 1310720);    // 655,360 B
    unsigned short* XT  = Xb + (size_t)NB * NT * DF;          // 655,360 B
    unsigned short* H1T = XT + (size_t)NB * NT * DF;          // 655,360 B

    prep<<<320, 256, 0, stream>>>(X, Xb, XT);
    k_layer<<<640, 256, 0, stream>>>(Xb, XT, X, Ws, Wn, bv, h1, H1T);
    k_layer<<<640, 256, 0, stream>>>(Xb, H1T, h1, Ws + DF * DF, Wn + DF * DF,
                                     bv + DF, out, nullptr);
}